// Round 13
// baseline (397.549 us; speedup 1.0000x reference)
//
#include <hip/hip_runtime.h>

#define N_NODES   50000
#define N_EDGES   800000
#define N_FEAT    128
#define HIDDEN    64
#define N_LAYERS  3
#define N_GRAPHS  512
#define N_CLASSES 10
#define BN_EPS    1e-5f
#define SCAN_BLK  196    // ceil(N_NODES/256)
#define LWAVES    8      // waves per block in enc/layer kernels (512 threads)
#define HP        32     // uints per bf16 h-row (64 cols * 2B = 128B)
#define NBLK      1024   // best measured config (R8): 8192 waves
#define NGRP      (N_NODES / 4)
#define QSCALE    65536.0f
#define QINV      (1.0f / 65536.0f)
#define SSCALE    1048576.0          // 2^20 stats fixed-point
#define SINV      (1.0 / 1048576.0)

// fp32 -> bf16 (RNE), returned in low 16 bits
__device__ __forceinline__ unsigned bf16rne(float x)
{
    unsigned u = __float_as_uint(x);
    return (u + 0x7fffu + ((u >> 16) & 1u)) >> 16;
}
// unpack bf16 pair: .x = low half (even col), .y = high half (odd col)
__device__ __forceinline__ float2 bf2(unsigned u)
{
    float2 r;
    r.x = __uint_as_float(u << 16);
    r.y = __uint_as_float(u & 0xffff0000u);
    return r;
}

// BN+ReLU one bf16x8 chunk then accumulate into int32 fixed-point (exact,
// permutation-invariant -> deterministic under csr_src order variation)
template<bool HASBN>
__device__ __forceinline__ void accrow_bn(int (&a)[8], uint4 u,
                                          const float (&Ag)[8], const float (&Bg)[8])
{
    float2 f0 = bf2(u.x), f1 = bf2(u.y), f2 = bf2(u.z), f3 = bf2(u.w);
    float v[8] = {f0.x, f0.y, f1.x, f1.y, f2.x, f2.y, f3.x, f3.y};
    #pragma unroll
    for (int t = 0; t < 8; ++t) {
        float f = v[t];
        if (HASBN) f = fmaxf(fmaf(f, Ag[t], Bg[t]), 0.f);
        a[t] += (int)(f * QSCALE);
    }
}

// BN affine consts from int64 fixed-point stats (deterministic)
__device__ __forceinline__ void bn_const(const unsigned long long* stats,
                                         const float* gamma, const float* beta,
                                         int c, float& A, float& B)
{
    double m  = (double)(long long)stats[c]          * (SINV / (double)N_NODES);
    double e2 = (double)(long long)stats[HIDDEN + c] * (SINV / (double)N_NODES);
    float mean = (float)m;
    float var  = (float)(e2 - m * m);
    float inv  = rsqrtf(fmaxf(var, 0.f) + BN_EPS);
    A = inv * gamma[c];
    B = beta[c] - mean * A;
}

// ---------------- encoder: h = x @ enc_w + enc_b -> bf16 h -----------------
__global__ __launch_bounds__(512, 6) void enc_kernel(
    const float* __restrict__ x, const float* __restrict__ w,
    const float* __restrict__ b, unsigned* __restrict__ h,
    int* __restrict__ deg)
{
    __shared__ __align__(16) float wT[HIDDEN * N_FEAT];        // 32 KB swizzled
    __shared__ __align__(16) float xb[LWAVES][4][N_FEAT];      // 16 KB
    {   // fold: zero deg for the CSR histogram
        int g = blockIdx.x * 512 + threadIdx.x;
        if (g < N_NODES) deg[g] = 0;
    }
    // bank-balanced swizzle: sz includes lane>>4 so lanes sharing (lane&15)
    // land in different banks (2-way max aliasing = free)
    for (int i = threadIdx.x; i < N_FEAT * HIDDEN; i += 512) {
        int k = i >> 6, c = i & 63;
        int szc = (c & 15) ^ ((c >> 4) << 2);
        wT[c * 128 + (((k >> 2) ^ szc) << 2) + (k & 3)] = w[i];
    }
    const int lane = threadIdx.x & 63;
    const int wv   = threadIdx.x >> 6;
    const int sz   = (lane & 15) ^ ((lane >> 4) << 2);
    const int r2   = lane >> 5;          // 0..1
    const int cc   = (lane & 31) * 4;    // 0..124
    const float bias = b[lane];
    __syncthreads();
    const int nwaves = gridDim.x * LWAVES;
    for (int grp = blockIdx.x * LWAVES + wv; grp < NGRP; grp += nwaves) {
        const int nbase = grp * 4;
        float4 v0 = *(const float4*)&x[(size_t)(nbase + r2) * N_FEAT + cc];
        float4 v1 = *(const float4*)&x[(size_t)(nbase + 2 + r2) * N_FEAT + cc];
        *((float4*)&xb[wv][r2][cc])     = v0;
        *((float4*)&xb[wv][2 + r2][cc]) = v1;
        float o0 = bias, o1 = bias, o2 = bias, o3 = bias;
        #pragma unroll 8
        for (int kc = 0; kc < N_FEAT / 4; ++kc) {
            float4 w4 = *(const float4*)&wT[lane * 128 + ((kc ^ sz) << 2)];
            float4 z0 = *(const float4*)&xb[wv][0][4 * kc];
            float4 z1 = *(const float4*)&xb[wv][1][4 * kc];
            float4 z2 = *(const float4*)&xb[wv][2][4 * kc];
            float4 z3 = *(const float4*)&xb[wv][3][4 * kc];
            o0 = fmaf(w4.x, z0.x, fmaf(w4.y, z0.y, fmaf(w4.z, z0.z, fmaf(w4.w, z0.w, o0))));
            o1 = fmaf(w4.x, z1.x, fmaf(w4.y, z1.y, fmaf(w4.z, z1.z, fmaf(w4.w, z1.w, o1))));
            o2 = fmaf(w4.x, z2.x, fmaf(w4.y, z2.y, fmaf(w4.z, z2.z, fmaf(w4.w, z2.w, o2))));
            o3 = fmaf(w4.x, z3.x, fmaf(w4.y, z3.y, fmaf(w4.z, z3.z, fmaf(w4.w, z3.w, o3))));
        }
        float t0 = __shfl_xor(o0, 1), t1 = __shfl_xor(o1, 1);
        float t2 = __shfl_xor(o2, 1), t3 = __shfl_xor(o3, 1);
        if (!(lane & 1)) {
            int p = lane >> 1;
            h[(size_t)(nbase + 0) * HP + p] = bf16rne(o0) | (bf16rne(t0) << 16);
            h[(size_t)(nbase + 1) * HP + p] = bf16rne(o1) | (bf16rne(t1) << 16);
            h[(size_t)(nbase + 2) * HP + p] = bf16rne(o2) | (bf16rne(t2) << 16);
            h[(size_t)(nbase + 3) * HP + p] = bf16rne(o3) | (bf16rne(t3) << 16);
        }
    }
}

// ---------------- CSR build ------------------------------------------------
__global__ __launch_bounds__(256) void hist_kernel(const int* __restrict__ ei,
                                                   int* __restrict__ deg,
                                                   unsigned long long* __restrict__ stats)
{
    if (blockIdx.x == 0) {   // fold: zero int64 stats
        for (int i = threadIdx.x; i < N_LAYERS * 2 * HIDDEN; i += 256) stats[i] = 0ull;
    }
    int e = blockIdx.x * 256 + threadIdx.x;
    if (e < N_EDGES) atomicAdd(&deg[ei[N_EDGES + e]], 1);
}

__global__ __launch_bounds__(256) void scan1_kernel(const int* __restrict__ deg,
                                                    int* __restrict__ row_start,
                                                    int* __restrict__ bsum)
{
    __shared__ int s[256];
    const int tid = threadIdx.x;
    const int gid = blockIdx.x * 256 + tid;
    int v = (gid < N_NODES) ? deg[gid] : 0;
    s[tid] = v;
    __syncthreads();
    for (int off = 1; off < 256; off <<= 1) {
        int t = (tid >= off) ? s[tid - off] : 0;
        __syncthreads();
        if (tid >= off) s[tid] += t;
        __syncthreads();
    }
    if (gid < N_NODES) row_start[gid] = s[tid] - v;
    if (tid == 255) bsum[blockIdx.x] = s[255];
}

__global__ __launch_bounds__(256) void scan2_kernel(int* __restrict__ bsum,
                                                    int* __restrict__ row_start)
{
    __shared__ int s[256];
    const int tid = threadIdx.x;
    int v = (tid < SCAN_BLK) ? bsum[tid] : 0;
    s[tid] = v;
    __syncthreads();
    for (int off = 1; off < 256; off <<= 1) {
        int t = (tid >= off) ? s[tid - off] : 0;
        __syncthreads();
        if (tid >= off) s[tid] += t;
        __syncthreads();
    }
    if (tid < SCAN_BLK) bsum[tid] = s[tid] - v;
    if (tid == 255) row_start[N_NODES] = s[255];
}

__global__ __launch_bounds__(256) void scan3_kernel(int* __restrict__ row_start,
                                                    const int* __restrict__ bsum,
                                                    int* __restrict__ cursor)
{
    int gid = blockIdx.x * 256 + threadIdx.x;
    if (gid < N_NODES) {
        int v = row_start[gid] + bsum[blockIdx.x];
        row_start[gid] = v;
        cursor[gid] = v;
    }
}

__global__ __launch_bounds__(256) void fill_kernel(const int* __restrict__ ei,
                                                   int* __restrict__ cursor,
                                                   int* __restrict__ csr_src)
{
    int e = blockIdx.x * 256 + threadIdx.x;
    if (e >= N_EDGES) return;
    int d = ei[N_EDGES + e];
    int pos = atomicAdd(&cursor[d], 1);
    csr_src[pos] = ei[e];
}

// ---------------- fused GIN layer (bf16 h, BN folded into gather) ----------
// R8-best structure: BN+ReLU applied per gathered row (no separate bn_apply
// pass), int32 fixed-point gather accumulate, int64 fixed-point stats atomics.
template<bool HASBN>
__global__ __launch_bounds__(512, 8) void layer_kernel(
    const unsigned* __restrict__ hin, const int* __restrict__ csr_src,
    const int* __restrict__ row_start,
    const unsigned long long* __restrict__ stats_prev,
    const float* __restrict__ gamma, const float* __restrict__ beta,
    const float* __restrict__ eps, int layer,
    const float* __restrict__ w1, const float* __restrict__ b1,
    const float* __restrict__ w2, const float* __restrict__ b2,
    unsigned* __restrict__ hout, unsigned long long* __restrict__ stats_cur)
{
    __shared__ __align__(16) float wT1[HIDDEN * HIDDEN];       // 16 KB swizzled
    __shared__ __align__(16) float wT2[HIDDEN * HIDDEN];       // 16 KB swizzled
    __shared__ __align__(16) float zb[LWAVES][4][HIDDEN];      // 8 KB wave-private
    for (int i = threadIdx.x; i < HIDDEN * HIDDEN; i += 512) {
        int k = i >> 6, c = i & 63;
        int szc = (c & 15) ^ ((c >> 4) << 2);
        int dst = c * 64 + (((k >> 2) ^ szc) << 2) + (k & 3);
        wT1[dst] = w1[i];
        wT2[dst] = w2[i];
    }
    const int lane = threadIdx.x & 63;
    const int wv   = threadIdx.x >> 6;
    const int o    = lane >> 3;          // 0..7: row within oct
    const int c8   = (lane & 7) * 4;     // uint offset in row (8 bf16 cols)
    const int cb   = c8 * 2;
    const int sz   = (lane & 15) ^ ((lane >> 4) << 2);
    float Ag[8], Bg[8];
    #pragma unroll
    for (int t = 0; t < 8; ++t) { Ag[t] = 1.f; Bg[t] = 0.f; }
    if (HASBN) {
        #pragma unroll
        for (int t = 0; t < 8; ++t)
            bn_const(stats_prev, gamma, beta, cb + t, Ag[t], Bg[t]);
    }
    const float sf  = 1.0f + eps[layer];
    const float b1c = b1[lane], b2c = b2[lane];
    __syncthreads();

    long long sAcc = 0, s2Acc = 0;
    const int nwaves = gridDim.x * LWAVES;
    for (int grp = blockIdx.x * LWAVES + wv; grp < NGRP; grp += nwaves) {
        const int nbase = grp * 4;
        // one coalesced load covers all 5 row bounds of the group
        const int rsv = row_start[nbase + (lane < 5 ? lane : 0)];
        #pragma unroll
        for (int n = 0; n < 4; ++n) {
            const int node = nbase + n;
            const int s0 = __shfl(rsv, n);
            const int s1 = __shfl(rsv, n + 1);
            // self row hoisted: stays in flight across the neighbor gather
            const uint4 su = *(const uint4*)&hin[(size_t)node * HP + c8];
            int a[8];
            #pragma unroll
            for (int t = 0; t < 8; ++t) a[t] = 0;
            for (int jb = s0; jb < s1; jb += 64) {
                int m = s1 - jb; if (m > 64) m = 64;
                int idx = csr_src[jb + (lane < m ? lane : m - 1)];
                int mm = m & ~7;
                int j = 0;
                // 2-deep: two independent row loads in flight per iteration
                for (; j + 16 <= mm; j += 16) {
                    int i0 = __shfl(idx, j + o);
                    int i1 = __shfl(idx, j + 8 + o);
                    uint4 u0 = *(const uint4*)&hin[(size_t)i0 * HP + c8];
                    uint4 u1 = *(const uint4*)&hin[(size_t)i1 * HP + c8];
                    accrow_bn<HASBN>(a, u0, Ag, Bg);
                    accrow_bn<HASBN>(a, u1, Ag, Bg);
                }
                for (; j < mm; j += 8) {
                    int i = __shfl(idx, j + o);
                    uint4 u = *(const uint4*)&hin[(size_t)i * HP + c8];
                    accrow_bn<HASBN>(a, u, Ag, Bg);
                }
                int r8 = m & 7;
                if (r8) {
                    int sl = mm + o;
                    int i = __shfl(idx, sl < m ? sl : m - 1);
                    if (o < r8) {
                        uint4 u = *(const uint4*)&hin[(size_t)i * HP + c8];
                        accrow_bn<HASBN>(a, u, Ag, Bg);
                    }
                }
            }
            // oct reduction (int: exact, order-free)
            #pragma unroll
            for (int t = 0; t < 8; ++t) {
                a[t] += __shfl_xor(a[t], 8);
                a[t] += __shfl_xor(a[t], 16);
                a[t] += __shfl_xor(a[t], 32);
            }
            if (o == 0) {
                float2 g0 = bf2(su.x), g1 = bf2(su.y), g2 = bf2(su.z), g3 = bf2(su.w);
                float svv[8] = {g0.x, g0.y, g1.x, g1.y, g2.x, g2.y, g3.x, g3.y};
                float zo[8];
                #pragma unroll
                for (int t = 0; t < 8; ++t) {
                    float f = svv[t];
                    if (HASBN) f = fmaxf(fmaf(f, Ag[t], Bg[t]), 0.f);
                    zo[t] = fmaf(sf, f, (float)a[t] * QINV);
                }
                float4 q0 = {zo[0], zo[1], zo[2], zo[3]};
                float4 q1 = {zo[4], zo[5], zo[6], zo[7]};
                *((float4*)&zb[wv][n][cb])     = q0;
                *((float4*)&zb[wv][n][cb + 4]) = q1;
            }
        }
        // ---- MLP1: o = relu(z @ w1 + b1) ----
        float o0 = b1c, o1 = b1c, o2 = b1c, o3 = b1c;
        #pragma unroll 4
        for (int kc = 0; kc < HIDDEN / 4; ++kc) {
            float4 w4 = *(const float4*)&wT1[lane * 64 + ((kc ^ sz) << 2)];
            float4 z0 = *(const float4*)&zb[wv][0][4 * kc];
            float4 z1 = *(const float4*)&zb[wv][1][4 * kc];
            float4 z2 = *(const float4*)&zb[wv][2][4 * kc];
            float4 z3 = *(const float4*)&zb[wv][3][4 * kc];
            o0 = fmaf(w4.x, z0.x, fmaf(w4.y, z0.y, fmaf(w4.z, z0.z, fmaf(w4.w, z0.w, o0))));
            o1 = fmaf(w4.x, z1.x, fmaf(w4.y, z1.y, fmaf(w4.z, z1.z, fmaf(w4.w, z1.w, o1))));
            o2 = fmaf(w4.x, z2.x, fmaf(w4.y, z2.y, fmaf(w4.z, z2.z, fmaf(w4.w, z2.w, o2))));
            o3 = fmaf(w4.x, z3.x, fmaf(w4.y, z3.y, fmaf(w4.z, z3.z, fmaf(w4.w, z3.w, o3))));
        }
        zb[wv][0][lane] = fmaxf(o0, 0.f);
        zb[wv][1][lane] = fmaxf(o1, 0.f);
        zb[wv][2][lane] = fmaxf(o2, 0.f);
        zb[wv][3][lane] = fmaxf(o3, 0.f);
        // ---- MLP2: p = y @ w2 + b2 ----
        float p0 = b2c, p1 = b2c, p2 = b2c, p3 = b2c;
        #pragma unroll 4
        for (int kc = 0; kc < HIDDEN / 4; ++kc) {
            float4 w4 = *(const float4*)&wT2[lane * 64 + ((kc ^ sz) << 2)];
            float4 z0 = *(const float4*)&zb[wv][0][4 * kc];
            float4 z1 = *(const float4*)&zb[wv][1][4 * kc];
            float4 z2 = *(const float4*)&zb[wv][2][4 * kc];
            float4 z3 = *(const float4*)&zb[wv][3][4 * kc];
            p0 = fmaf(w4.x, z0.x, fmaf(w4.y, z0.y, fmaf(w4.z, z0.z, fmaf(w4.w, z0.w, p0))));
            p1 = fmaf(w4.x, z1.x, fmaf(w4.y, z1.y, fmaf(w4.z, z1.z, fmaf(w4.w, z1.w, p1))));
            p2 = fmaf(w4.x, z2.x, fmaf(w4.y, z2.y, fmaf(w4.z, z2.z, fmaf(w4.w, z2.w, p2))));
            p3 = fmaf(w4.x, z3.x, fmaf(w4.y, z3.y, fmaf(w4.z, z3.z, fmaf(w4.w, z3.w, p3))));
        }
        float t0 = __shfl_xor(p0, 1), t1 = __shfl_xor(p1, 1);
        float t2 = __shfl_xor(p2, 1), t3 = __shfl_xor(p3, 1);
        if (!(lane & 1)) {
            int p = lane >> 1;
            hout[(size_t)(nbase + 0) * HP + p] = bf16rne(p0) | (bf16rne(t0) << 16);
            hout[(size_t)(nbase + 1) * HP + p] = bf16rne(p1) | (bf16rne(t1) << 16);
            hout[(size_t)(nbase + 2) * HP + p] = bf16rne(p2) | (bf16rne(t2) << 16);
            hout[(size_t)(nbase + 3) * HP + p] = bf16rne(p3) | (bf16rne(t3) << 16);
        }
        // per-group stats in int64 fixed-point (fixed intra-group fp order)
        float g1 = (p0 + p1) + (p2 + p3);
        float g2 = (p0 * p0 + p1 * p1) + (p2 * p2 + p3 * p3);
        sAcc  += (long long)((double)g1 * SSCALE);
        s2Acc += (long long)((double)g2 * SSCALE);
    }
    // ---- block-level int64 reduction (exact) + one atomic per col ----
    __syncthreads();
    long long* red = (long long*)&zb[0][0][0];   // 1024 * 8B = 8 KB
    red[threadIdx.x]       = sAcc;
    red[512 + threadIdx.x] = s2Acc;
    __syncthreads();
    if (wv == 0) {
        long long ts = 0, ts2 = 0;
        #pragma unroll
        for (int wq = 0; wq < LWAVES; ++wq) {
            ts  += red[wq * 64 + lane];
            ts2 += red[512 + wq * 64 + lane];
        }
        atomicAdd((unsigned long long*)&stats_cur[lane],          (unsigned long long)ts);
        atomicAdd((unsigned long long*)&stats_cur[HIDDEN + lane], (unsigned long long)ts2);
    }
}

__device__ __forceinline__ int lbound(const int* __restrict__ a, int n, int v)
{
    int lo = 0, hi = n;
    while (lo < hi) { int m = (lo + hi) >> 1; if (a[m] < v) lo = m + 1; else hi = m; }
    return lo;
}

// ---------------- mean pool per graph + final linear (fused) ---------------
__global__ __launch_bounds__(256) void pool_out_kernel(
    const unsigned* __restrict__ hpre, const int* __restrict__ batch,
    const unsigned long long* __restrict__ stats, const float* __restrict__ gamma,
    const float* __restrict__ beta, const float* __restrict__ lw,
    const float* __restrict__ lb, float* __restrict__ out)
{
    __shared__ int bounds[2];
    __shared__ float red[256];
    __shared__ float pv[64];
    const int g = blockIdx.x;
    if (threadIdx.x < 2)
        bounds[threadIdx.x] = lbound(batch, N_NODES, g + threadIdx.x);
    __syncthreads();
    const int start = bounds[0], end = bounds[1];
    const int col = threadIdx.x & 63;
    const int row = threadIdx.x >> 6;
    float A, B;
    bn_const(stats, gamma, beta, col, A, B);
    float s = 0.f;
    for (int r = start + row; r < end; r += 4) {
        unsigned u = hpre[(size_t)r * HP + (col >> 1)];
        float v = (col & 1) ? __uint_as_float(u & 0xffff0000u)
                            : __uint_as_float(u << 16);
        s += fmaxf(fmaf(v, A, B), 0.f);
    }
    red[threadIdx.x] = s;
    __syncthreads();
    if (row == 0) {
        float t = red[col] + red[64 + col] + red[128 + col] + red[192 + col];
        pv[col] = t / fmaxf((float)(end - start), 1.0f);
    }
    __syncthreads();
    if (threadIdx.x < N_CLASSES) {
        float acc = lb[threadIdx.x];
        #pragma unroll 16
        for (int j = 0; j < HIDDEN; ++j)
            acc = fmaf(pv[j], lw[j * N_CLASSES + threadIdx.x], acc);
        out[g * N_CLASSES + threadIdx.x] = acc;
    }
}

extern "C" void kernel_launch(void* const* d_in, const int* in_sizes, int n_in,
                              void* d_out, int out_size, void* d_ws, size_t ws_size,
                              hipStream_t stream)
{
    const float* x       = (const float*)d_in[0];
    const int*   ei      = (const int*)d_in[1];   // [2, N_EDGES]: src then dst
    const int*   batch   = (const int*)d_in[2];
    const float* enc_w   = (const float*)d_in[3];
    const float* enc_b   = (const float*)d_in[4];
    const float* eps     = (const float*)d_in[5];
    const float* conv_w1 = (const float*)d_in[6];
    const float* conv_b1 = (const float*)d_in[7];
    const float* conv_w2 = (const float*)d_in[8];
    const float* conv_b2 = (const float*)d_in[9];
    const float* bn_g    = (const float*)d_in[10];
    const float* bn_b    = (const float*)d_in[11];
    const float* lin_w   = (const float*)d_in[12];
    const float* lin_b   = (const float*)d_in[13];
    float* out = (float*)d_out;

    char* ws = (char*)d_ws;
    const size_t HB = (size_t)N_NODES * HP * sizeof(unsigned);  // 6.4 MB bf16 rows
    size_t off = 0;
    unsigned* P    = (unsigned*)(ws + off); off += HB;       // ping
    unsigned* Q    = (unsigned*)(ws + off); off += HB;       // pong
    unsigned long long* stats64 = (unsigned long long*)(ws + off);
    off += N_LAYERS * 2 * HIDDEN * sizeof(unsigned long long);
    int* deg       = (int*)(ws + off); off += 50176 * sizeof(int);
    int* row_start = (int*)(ws + off); off += 50176 * sizeof(int);   // N_NODES+1 used
    int* cursor    = (int*)(ws + off); off += 50176 * sizeof(int);
    int* bsum      = (int*)(ws + off); off += 256 * sizeof(int);
    int* csr_src   = (int*)(ws + off); off += (size_t)N_EDGES * sizeof(int);

    // enc zeroes deg; hist zeroes stats64 (stream-ordered before use)
    enc_kernel<<<768, 512, 0, stream>>>(x, enc_w, enc_b, P, deg);

    hist_kernel<<<(N_EDGES + 255) / 256, 256, 0, stream>>>(ei, deg, stats64);
    scan1_kernel<<<SCAN_BLK, 256, 0, stream>>>(deg, row_start, bsum);
    scan2_kernel<<<1, 256, 0, stream>>>(bsum, row_start);
    scan3_kernel<<<SCAN_BLK, 256, 0, stream>>>(row_start, bsum, cursor);
    fill_kernel<<<(N_EDGES + 255) / 256, 256, 0, stream>>>(ei, cursor, csr_src);

    const unsigned* curin = P;
    unsigned* curout = Q;
    for (int l = 0; l < N_LAYERS; ++l) {
        const float* w1 = conv_w1 + (size_t)l * HIDDEN * HIDDEN;
        const float* b1 = conv_b1 + (size_t)l * HIDDEN;
        const float* w2 = conv_w2 + (size_t)l * HIDDEN * HIDDEN;
        const float* b2 = conv_b2 + (size_t)l * HIDDEN;
        if (l == 0)
            layer_kernel<false><<<NBLK, 512, 0, stream>>>(
                curin, csr_src, row_start, nullptr, nullptr, nullptr,
                eps, l, w1, b1, w2, b2, curout, stats64);
        else
            layer_kernel<true><<<NBLK, 512, 0, stream>>>(
                curin, csr_src, row_start,
                stats64 + (size_t)(l - 1) * 2 * HIDDEN,
                bn_g + (size_t)(l - 1) * HIDDEN, bn_b + (size_t)(l - 1) * HIDDEN,
                eps, l, w1, b1, w2, b2, curout,
                stats64 + (size_t)l * 2 * HIDDEN);
        const unsigned* t = curout; curout = (unsigned*)curin; curin = t;
    }
    // after 3 layers: final pre-BN activations are in Q (P->Q->P->Q)

    pool_out_kernel<<<N_GRAPHS, 256, 0, stream>>>(
        Q, batch, stats64 + (size_t)(N_LAYERS - 1) * 2 * HIDDEN,
        bn_g + (size_t)(N_LAYERS - 1) * HIDDEN, bn_b + (size_t)(N_LAYERS - 1) * HIDDEN,
        lin_w, lin_b, out);
}

// Round 14
// 349.660 us; speedup vs baseline: 1.1370x; 1.1370x over previous
//
#include <hip/hip_runtime.h>

#define N_NODES   50000
#define N_EDGES   800000
#define N_FEAT    128
#define HIDDEN    64
#define N_LAYERS  3
#define N_GRAPHS  512
#define N_CLASSES 10
#define BN_EPS    1e-5f
#define SCAN_BLK  196    // ceil(N_NODES/256)
#define LWAVES    8      // waves per block in enc/layer kernels (512 threads)
#define HP        32     // uints per bf16 h-row (64 cols * 2B = 128B)
#define NBLK      1024   // best measured config (R8): 8192 waves
#define NGRP      (N_NODES / 4)
#define QSCALE    65536.0f
#define QINV      (1.0f / 65536.0f)
#define SSCALE    1048576.0          // 2^20 stats fixed-point
#define SINV      (1.0 / 1048576.0)

// 16B-group XOR swizzle within a row (R8's proven form)
__device__ __forceinline__ int swz(int c, int g) { return g ^ (c & 15); }

// fp32 -> bf16 (RNE), returned in low 16 bits
__device__ __forceinline__ unsigned bf16rne(float x)
{
    unsigned u = __float_as_uint(x);
    return (u + 0x7fffu + ((u >> 16) & 1u)) >> 16;
}
// unpack bf16 pair: .x = low half (even col), .y = high half (odd col)
__device__ __forceinline__ float2 bf2(unsigned u)
{
    float2 r;
    r.x = __uint_as_float(u << 16);
    r.y = __uint_as_float(u & 0xffff0000u);
    return r;
}

// BN affine consts from int64 fixed-point stats (deterministic)
__device__ __forceinline__ void bn_const(const unsigned long long* stats,
                                         const float* gamma, const float* beta,
                                         int c, float& A, float& B)
{
    double m  = (double)(long long)stats[c]          * (SINV / (double)N_NODES);
    double e2 = (double)(long long)stats[HIDDEN + c] * (SINV / (double)N_NODES);
    float mean = (float)m;
    float var  = (float)(e2 - m * m);
    float inv  = rsqrtf(fmaxf(var, 0.f) + BN_EPS);
    A = inv * gamma[c];
    B = beta[c] - mean * A;
}

// ---------------- encoder: h = x @ enc_w + enc_b -> bf16 h -----------------
__global__ __launch_bounds__(512, 6) void enc_kernel(
    const float* __restrict__ x, const float* __restrict__ w,
    const float* __restrict__ b, unsigned* __restrict__ h,
    int* __restrict__ deg)
{
    __shared__ __align__(16) float wT[HIDDEN * N_FEAT];        // 32 KB swizzled
    __shared__ __align__(16) float xb[LWAVES][4][N_FEAT];      // 16 KB
    {   // fold: zero deg for the CSR histogram
        int g = blockIdx.x * 512 + threadIdx.x;
        if (g < N_NODES) deg[g] = 0;
    }
    for (int i = threadIdx.x; i < N_FEAT * HIDDEN; i += 512) {
        int k = i >> 6, c = i & 63;
        wT[c * 128 + swz(c, k >> 2) * 4 + (k & 3)] = w[i];
    }
    const int lane = threadIdx.x & 63;
    const int wv   = threadIdx.x >> 6;
    const int sz   = lane & 15;
    const int r2   = lane >> 5;          // 0..1
    const int cc   = (lane & 31) * 4;    // 0..124
    const float bias = b[lane];
    __syncthreads();
    const int nwaves = gridDim.x * LWAVES;
    for (int grp = blockIdx.x * LWAVES + wv; grp < NGRP; grp += nwaves) {
        const int nbase = grp * 4;
        float4 v0 = *(const float4*)&x[(size_t)(nbase + r2) * N_FEAT + cc];
        float4 v1 = *(const float4*)&x[(size_t)(nbase + 2 + r2) * N_FEAT + cc];
        *((float4*)&xb[wv][r2][cc])     = v0;
        *((float4*)&xb[wv][2 + r2][cc]) = v1;
        float o0 = bias, o1 = bias, o2 = bias, o3 = bias;
        #pragma unroll 8
        for (int kc = 0; kc < N_FEAT / 4; ++kc) {
            float4 w4 = *(const float4*)&wT[lane * 128 + ((kc ^ sz) << 2)];
            float4 z0 = *(const float4*)&xb[wv][0][4 * kc];
            float4 z1 = *(const float4*)&xb[wv][1][4 * kc];
            float4 z2 = *(const float4*)&xb[wv][2][4 * kc];
            float4 z3 = *(const float4*)&xb[wv][3][4 * kc];
            o0 = fmaf(w4.x, z0.x, fmaf(w4.y, z0.y, fmaf(w4.z, z0.z, fmaf(w4.w, z0.w, o0))));
            o1 = fmaf(w4.x, z1.x, fmaf(w4.y, z1.y, fmaf(w4.z, z1.z, fmaf(w4.w, z1.w, o1))));
            o2 = fmaf(w4.x, z2.x, fmaf(w4.y, z2.y, fmaf(w4.z, z2.z, fmaf(w4.w, z2.w, o2))));
            o3 = fmaf(w4.x, z3.x, fmaf(w4.y, z3.y, fmaf(w4.z, z3.z, fmaf(w4.w, z3.w, o3))));
        }
        float t0 = __shfl_xor(o0, 1), t1 = __shfl_xor(o1, 1);
        float t2 = __shfl_xor(o2, 1), t3 = __shfl_xor(o3, 1);
        if (!(lane & 1)) {
            int p = lane >> 1;
            h[(size_t)(nbase + 0) * HP + p] = bf16rne(o0) | (bf16rne(t0) << 16);
            h[(size_t)(nbase + 1) * HP + p] = bf16rne(o1) | (bf16rne(t1) << 16);
            h[(size_t)(nbase + 2) * HP + p] = bf16rne(o2) | (bf16rne(t2) << 16);
            h[(size_t)(nbase + 3) * HP + p] = bf16rne(o3) | (bf16rne(t3) << 16);
        }
    }
}

// ---------------- CSR build ------------------------------------------------
__global__ __launch_bounds__(256) void hist_kernel(const int* __restrict__ ei,
                                                   int* __restrict__ deg,
                                                   unsigned long long* __restrict__ stats)
{
    if (blockIdx.x == 0) {   // fold: zero int64 stats
        for (int i = threadIdx.x; i < N_LAYERS * 2 * HIDDEN; i += 256) stats[i] = 0ull;
    }
    int e = blockIdx.x * 256 + threadIdx.x;
    if (e < N_EDGES) atomicAdd(&deg[ei[N_EDGES + e]], 1);
}

__global__ __launch_bounds__(256) void scan1_kernel(const int* __restrict__ deg,
                                                    int* __restrict__ row_start,
                                                    int* __restrict__ bsum)
{
    __shared__ int s[256];
    const int tid = threadIdx.x;
    const int gid = blockIdx.x * 256 + tid;
    int v = (gid < N_NODES) ? deg[gid] : 0;
    s[tid] = v;
    __syncthreads();
    for (int off = 1; off < 256; off <<= 1) {
        int t = (tid >= off) ? s[tid - off] : 0;
        __syncthreads();
        if (tid >= off) s[tid] += t;
        __syncthreads();
    }
    if (gid < N_NODES) row_start[gid] = s[tid] - v;
    if (tid == 255) bsum[blockIdx.x] = s[255];
}

__global__ __launch_bounds__(256) void scan2_kernel(int* __restrict__ bsum,
                                                    int* __restrict__ row_start)
{
    __shared__ int s[256];
    const int tid = threadIdx.x;
    int v = (tid < SCAN_BLK) ? bsum[tid] : 0;
    s[tid] = v;
    __syncthreads();
    for (int off = 1; off < 256; off <<= 1) {
        int t = (tid >= off) ? s[tid - off] : 0;
        __syncthreads();
        if (tid >= off) s[tid] += t;
        __syncthreads();
    }
    if (tid < SCAN_BLK) bsum[tid] = s[tid] - v;
    if (tid == 255) row_start[N_NODES] = s[255];
}

__global__ __launch_bounds__(256) void scan3_kernel(int* __restrict__ row_start,
                                                    const int* __restrict__ bsum,
                                                    int* __restrict__ cursor)
{
    int gid = blockIdx.x * 256 + threadIdx.x;
    if (gid < N_NODES) {
        int v = row_start[gid] + bsum[blockIdx.x];
        row_start[gid] = v;
        cursor[gid] = v;
    }
}

__global__ __launch_bounds__(256) void fill_kernel(const int* __restrict__ ei,
                                                   int* __restrict__ cursor,
                                                   int* __restrict__ csr_src)
{
    int e = blockIdx.x * 256 + threadIdx.x;
    if (e >= N_EDGES) return;
    int d = ei[N_EDGES + e];
    int pos = atomicAdd(&cursor[d], 1);
    csr_src[pos] = ei[e];
}

// ---------------- fused GIN layer — R8's measured-best structure ------------
// Simple one-load-per-j-step gather, BN+ReLU folded into the gathered reads,
// int32 fixed-point accumulate (permutation-invariant), int64 fixed-point
// stats atomics (order-free, deterministic).
template<bool HASBN>
__global__ __launch_bounds__(512, 8) void layer_kernel(
    const unsigned* __restrict__ hin, const int* __restrict__ csr_src,
    const int* __restrict__ row_start,
    const unsigned long long* __restrict__ stats_prev,
    const float* __restrict__ gamma, const float* __restrict__ beta,
    const float* __restrict__ eps, int layer,
    const float* __restrict__ w1, const float* __restrict__ b1,
    const float* __restrict__ w2, const float* __restrict__ b2,
    unsigned* __restrict__ hout, unsigned long long* __restrict__ stats_cur)
{
    __shared__ __align__(16) float wT1[HIDDEN * HIDDEN];       // 16 KB swizzled
    __shared__ __align__(16) float wT2[HIDDEN * HIDDEN];       // 16 KB swizzled
    __shared__ __align__(16) float zb[LWAVES][4][HIDDEN];      // 8 KB wave-private
    for (int i = threadIdx.x; i < HIDDEN * HIDDEN; i += 512) {
        int k = i >> 6, c = i & 63;
        int dst = c * 64 + swz(c, k >> 2) * 4 + (k & 3);
        wT1[dst] = w1[i];
        wT2[dst] = w2[i];
    }
    const int lane = threadIdx.x & 63;
    const int wv   = threadIdx.x >> 6;
    const int o    = lane >> 3;          // 0..7: row within oct
    const int c8   = (lane & 7) * 4;     // uint offset in row (8 bf16 cols)
    const int cb   = c8 * 2;
    const int sz   = lane & 15;
    float Ag[8], Bg[8];
    #pragma unroll
    for (int t = 0; t < 8; ++t) { Ag[t] = 1.f; Bg[t] = 0.f; }
    if (HASBN) {
        #pragma unroll
        for (int t = 0; t < 8; ++t)
            bn_const(stats_prev, gamma, beta, cb + t, Ag[t], Bg[t]);
    }
    const float sf  = 1.0f + eps[layer];
    const float b1c = b1[lane], b2c = b2[lane];
    __syncthreads();

    long long sAcc = 0, s2Acc = 0;
    const int nwaves = gridDim.x * LWAVES;
    for (int grp = blockIdx.x * LWAVES + wv; grp < NGRP; grp += nwaves) {
        const int nbase = grp * 4;
        #pragma unroll
        for (int n = 0; n < 4; ++n) {
            const int node = nbase + n;
            const int s0 = row_start[node];
            const int s1 = row_start[node + 1];
            int a[8];
            #pragma unroll
            for (int t = 0; t < 8; ++t) a[t] = 0;
            for (int jb = s0; jb < s1; jb += 64) {
                int m = s1 - jb; if (m > 64) m = 64;
                int idx = csr_src[jb + (lane < m ? lane : m - 1)];
                int mm = m & ~7;
                for (int j = 0; j < mm; j += 8) {
                    int i = __shfl(idx, j + o);
                    uint4 u = *(const uint4*)&hin[(size_t)i * HP + c8];
                    float2 f0 = bf2(u.x), f1 = bf2(u.y), f2 = bf2(u.z), f3 = bf2(u.w);
                    float v[8] = {f0.x, f0.y, f1.x, f1.y, f2.x, f2.y, f3.x, f3.y};
                    #pragma unroll
                    for (int t = 0; t < 8; ++t) {
                        float f = v[t];
                        if (HASBN) f = fmaxf(fmaf(f, Ag[t], Bg[t]), 0.f);
                        a[t] += (int)(f * QSCALE);
                    }
                }
                int r8 = m & 7;
                if (r8) {
                    int sl = mm + o;
                    int i = __shfl(idx, sl < m ? sl : m - 1);
                    if (o < r8) {
                        uint4 u = *(const uint4*)&hin[(size_t)i * HP + c8];
                        float2 f0 = bf2(u.x), f1 = bf2(u.y), f2 = bf2(u.z), f3 = bf2(u.w);
                        float v[8] = {f0.x, f0.y, f1.x, f1.y, f2.x, f2.y, f3.x, f3.y};
                        #pragma unroll
                        for (int t = 0; t < 8; ++t) {
                            float f = v[t];
                            if (HASBN) f = fmaxf(fmaf(f, Ag[t], Bg[t]), 0.f);
                            a[t] += (int)(f * QSCALE);
                        }
                    }
                }
            }
            // oct reduction (int: exact, order-free)
            #pragma unroll
            for (int t = 0; t < 8; ++t) {
                a[t] += __shfl_xor(a[t], 8);
                a[t] += __shfl_xor(a[t], 16);
                a[t] += __shfl_xor(a[t], 32);
            }
            // self term + write z row (lanes 0..7 hold the full row)
            if (o == 0) {
                uint4 su = *(const uint4*)&hin[(size_t)node * HP + c8];
                float2 g0 = bf2(su.x), g1 = bf2(su.y), g2 = bf2(su.z), g3 = bf2(su.w);
                float svv[8] = {g0.x, g0.y, g1.x, g1.y, g2.x, g2.y, g3.x, g3.y};
                float zo[8];
                #pragma unroll
                for (int t = 0; t < 8; ++t) {
                    float f = svv[t];
                    if (HASBN) f = fmaxf(fmaf(f, Ag[t], Bg[t]), 0.f);
                    zo[t] = fmaf(sf, f, (float)a[t] * QINV);
                }
                float4 q0 = {zo[0], zo[1], zo[2], zo[3]};
                float4 q1 = {zo[4], zo[5], zo[6], zo[7]};
                *((float4*)&zb[wv][n][cb])     = q0;
                *((float4*)&zb[wv][n][cb + 4]) = q1;
            }
        }
        // ---- MLP1: o = relu(z @ w1 + b1) ----
        float o0 = b1c, o1 = b1c, o2 = b1c, o3 = b1c;
        #pragma unroll 4
        for (int kc = 0; kc < HIDDEN / 4; ++kc) {
            float4 w4 = *(const float4*)&wT1[lane * 64 + ((kc ^ sz) << 2)];
            float4 z0 = *(const float4*)&zb[wv][0][4 * kc];
            float4 z1 = *(const float4*)&zb[wv][1][4 * kc];
            float4 z2 = *(const float4*)&zb[wv][2][4 * kc];
            float4 z3 = *(const float4*)&zb[wv][3][4 * kc];
            o0 = fmaf(w4.x, z0.x, fmaf(w4.y, z0.y, fmaf(w4.z, z0.z, fmaf(w4.w, z0.w, o0))));
            o1 = fmaf(w4.x, z1.x, fmaf(w4.y, z1.y, fmaf(w4.z, z1.z, fmaf(w4.w, z1.w, o1))));
            o2 = fmaf(w4.x, z2.x, fmaf(w4.y, z2.y, fmaf(w4.z, z2.z, fmaf(w4.w, z2.w, o2))));
            o3 = fmaf(w4.x, z3.x, fmaf(w4.y, z3.y, fmaf(w4.z, z3.z, fmaf(w4.w, z3.w, o3))));
        }
        zb[wv][0][lane] = fmaxf(o0, 0.f);
        zb[wv][1][lane] = fmaxf(o1, 0.f);
        zb[wv][2][lane] = fmaxf(o2, 0.f);
        zb[wv][3][lane] = fmaxf(o3, 0.f);
        // ---- MLP2: p = y @ w2 + b2 ----
        float p0 = b2c, p1 = b2c, p2 = b2c, p3 = b2c;
        #pragma unroll 4
        for (int kc = 0; kc < HIDDEN / 4; ++kc) {
            float4 w4 = *(const float4*)&wT2[lane * 64 + ((kc ^ sz) << 2)];
            float4 z0 = *(const float4*)&zb[wv][0][4 * kc];
            float4 z1 = *(const float4*)&zb[wv][1][4 * kc];
            float4 z2 = *(const float4*)&zb[wv][2][4 * kc];
            float4 z3 = *(const float4*)&zb[wv][3][4 * kc];
            p0 = fmaf(w4.x, z0.x, fmaf(w4.y, z0.y, fmaf(w4.z, z0.z, fmaf(w4.w, z0.w, p0))));
            p1 = fmaf(w4.x, z1.x, fmaf(w4.y, z1.y, fmaf(w4.z, z1.z, fmaf(w4.w, z1.w, p1))));
            p2 = fmaf(w4.x, z2.x, fmaf(w4.y, z2.y, fmaf(w4.z, z2.z, fmaf(w4.w, z2.w, p2))));
            p3 = fmaf(w4.x, z3.x, fmaf(w4.y, z3.y, fmaf(w4.z, z3.z, fmaf(w4.w, z3.w, p3))));
        }
        float t0 = __shfl_xor(p0, 1), t1 = __shfl_xor(p1, 1);
        float t2 = __shfl_xor(p2, 1), t3 = __shfl_xor(p3, 1);
        if (!(lane & 1)) {
            int p = lane >> 1;
            hout[(size_t)(nbase + 0) * HP + p] = bf16rne(p0) | (bf16rne(t0) << 16);
            hout[(size_t)(nbase + 1) * HP + p] = bf16rne(p1) | (bf16rne(t1) << 16);
            hout[(size_t)(nbase + 2) * HP + p] = bf16rne(p2) | (bf16rne(t2) << 16);
            hout[(size_t)(nbase + 3) * HP + p] = bf16rne(p3) | (bf16rne(t3) << 16);
        }
        // per-group stats in int64 fixed-point (fixed intra-group fp order)
        float g1 = (p0 + p1) + (p2 + p3);
        float g2 = (p0 * p0 + p1 * p1) + (p2 * p2 + p3 * p3);
        sAcc  += (long long)((double)g1 * SSCALE);
        s2Acc += (long long)((double)g2 * SSCALE);
    }
    // ---- block-level int64 reduction (exact) + one atomic per col ----
    __syncthreads();
    long long* red = (long long*)&zb[0][0][0];   // 1024 * 8B = 8 KB
    red[threadIdx.x]       = sAcc;
    red[512 + threadIdx.x] = s2Acc;
    __syncthreads();
    if (wv == 0) {
        long long ts = 0, ts2 = 0;
        #pragma unroll
        for (int wq = 0; wq < LWAVES; ++wq) {
            ts  += red[wq * 64 + lane];
            ts2 += red[512 + wq * 64 + lane];
        }
        atomicAdd((unsigned long long*)&stats_cur[lane],          (unsigned long long)ts);
        atomicAdd((unsigned long long*)&stats_cur[HIDDEN + lane], (unsigned long long)ts2);
    }
}

__device__ __forceinline__ int lbound(const int* __restrict__ a, int n, int v)
{
    int lo = 0, hi = n;
    while (lo < hi) { int m = (lo + hi) >> 1; if (a[m] < v) lo = m + 1; else hi = m; }
    return lo;
}

// ---------------- mean pool per graph + final linear (fused) ---------------
__global__ __launch_bounds__(256) void pool_out_kernel(
    const unsigned* __restrict__ hpre, const int* __restrict__ batch,
    const unsigned long long* __restrict__ stats, const float* __restrict__ gamma,
    const float* __restrict__ beta, const float* __restrict__ lw,
    const float* __restrict__ lb, float* __restrict__ out)
{
    __shared__ int bounds[2];
    __shared__ float red[256];
    __shared__ float pv[64];
    const int g = blockIdx.x;
    if (threadIdx.x < 2)
        bounds[threadIdx.x] = lbound(batch, N_NODES, g + threadIdx.x);
    __syncthreads();
    const int start = bounds[0], end = bounds[1];
    const int col = threadIdx.x & 63;
    const int row = threadIdx.x >> 6;
    float A, B;
    bn_const(stats, gamma, beta, col, A, B);
    float s = 0.f;
    for (int r = start + row; r < end; r += 4) {
        unsigned u = hpre[(size_t)r * HP + (col >> 1)];
        float v = (col & 1) ? __uint_as_float(u & 0xffff0000u)
                            : __uint_as_float(u << 16);
        s += fmaxf(fmaf(v, A, B), 0.f);
    }
    red[threadIdx.x] = s;
    __syncthreads();
    if (row == 0) {
        float t = red[col] + red[64 + col] + red[128 + col] + red[192 + col];
        pv[col] = t / fmaxf((float)(end - start), 1.0f);
    }
    __syncthreads();
    if (threadIdx.x < N_CLASSES) {
        float acc = lb[threadIdx.x];
        #pragma unroll 16
        for (int j = 0; j < HIDDEN; ++j)
            acc = fmaf(pv[j], lw[j * N_CLASSES + threadIdx.x], acc);
        out[g * N_CLASSES + threadIdx.x] = acc;
    }
}

extern "C" void kernel_launch(void* const* d_in, const int* in_sizes, int n_in,
                              void* d_out, int out_size, void* d_ws, size_t ws_size,
                              hipStream_t stream)
{
    const float* x       = (const float*)d_in[0];
    const int*   ei      = (const int*)d_in[1];   // [2, N_EDGES]: src then dst
    const int*   batch   = (const int*)d_in[2];
    const float* enc_w   = (const float*)d_in[3];
    const float* enc_b   = (const float*)d_in[4];
    const float* eps     = (const float*)d_in[5];
    const float* conv_w1 = (const float*)d_in[6];
    const float* conv_b1 = (const float*)d_in[7];
    const float* conv_w2 = (const float*)d_in[8];
    const float* conv_b2 = (const float*)d_in[9];
    const float* bn_g    = (const float*)d_in[10];
    const float* bn_b    = (const float*)d_in[11];
    const float* lin_w   = (const float*)d_in[12];
    const float* lin_b   = (const float*)d_in[13];
    float* out = (float*)d_out;

    char* ws = (char*)d_ws;
    const size_t HB = (size_t)N_NODES * HP * sizeof(unsigned);  // 6.4 MB bf16 rows
    size_t off = 0;
    unsigned* P    = (unsigned*)(ws + off); off += HB;       // ping
    unsigned* Q    = (unsigned*)(ws + off); off += HB;       // pong
    unsigned long long* stats64 = (unsigned long long*)(ws + off);
    off += N_LAYERS * 2 * HIDDEN * sizeof(unsigned long long);
    int* deg       = (int*)(ws + off); off += 50176 * sizeof(int);
    int* row_start = (int*)(ws + off); off += 50176 * sizeof(int);   // N_NODES+1 used
    int* cursor    = (int*)(ws + off); off += 50176 * sizeof(int);
    int* bsum      = (int*)(ws + off); off += 256 * sizeof(int);
    int* csr_src   = (int*)(ws + off); off += (size_t)N_EDGES * sizeof(int);

    // enc zeroes deg; hist zeroes stats64 (stream-ordered before use)
    enc_kernel<<<768, 512, 0, stream>>>(x, enc_w, enc_b, P, deg);

    hist_kernel<<<(N_EDGES + 255) / 256, 256, 0, stream>>>(ei, deg, stats64);
    scan1_kernel<<<SCAN_BLK, 256, 0, stream>>>(deg, row_start, bsum);
    scan2_kernel<<<1, 256, 0, stream>>>(bsum, row_start);
    scan3_kernel<<<SCAN_BLK, 256, 0, stream>>>(row_start, bsum, cursor);
    fill_kernel<<<(N_EDGES + 255) / 256, 256, 0, stream>>>(ei, cursor, csr_src);

    const unsigned* curin = P;
    unsigned* curout = Q;
    for (int l = 0; l < N_LAYERS; ++l) {
        const float* w1 = conv_w1 + (size_t)l * HIDDEN * HIDDEN;
        const float* b1 = conv_b1 + (size_t)l * HIDDEN;
        const float* w2 = conv_w2 + (size_t)l * HIDDEN * HIDDEN;
        const float* b2 = conv_b2 + (size_t)l * HIDDEN;
        if (l == 0)
            layer_kernel<false><<<NBLK, 512, 0, stream>>>(
                curin, csr_src, row_start, nullptr, nullptr, nullptr,
                eps, l, w1, b1, w2, b2, curout, stats64);
        else
            layer_kernel<true><<<NBLK, 512, 0, stream>>>(
                curin, csr_src, row_start,
                stats64 + (size_t)(l - 1) * 2 * HIDDEN,
                bn_g + (size_t)(l - 1) * HIDDEN, bn_b + (size_t)(l - 1) * HIDDEN,
                eps, l, w1, b1, w2, b2, curout,
                stats64 + (size_t)l * 2 * HIDDEN);
        const unsigned* t = curout; curout = (unsigned*)curin; curin = t;
    }
    // after 3 layers: final pre-BN activations are in Q (P->Q->P->Q)

    pool_out_kernel<<<N_GRAPHS, 256, 0, stream>>>(
        Q, batch, stats64 + (size_t)(N_LAYERS - 1) * 2 * HIDDEN,
        bn_g + (size_t)(N_LAYERS - 1) * HIDDEN, bn_b + (size_t)(N_LAYERS - 1) * HIDDEN,
        lin_w, lin_b, out);
}

// Round 15
// 328.566 us; speedup vs baseline: 1.2100x; 1.0642x over previous
//
#include <hip/hip_runtime.h>

#define N_NODES   50000
#define N_EDGES   800000
#define N_FEAT    128
#define HIDDEN    64
#define N_LAYERS  3
#define N_GRAPHS  512
#define N_CLASSES 10
#define BN_EPS    1e-5f
#define SCAN_BLK  196    // ceil(N_NODES/256)
#define LWAVES    8      // waves per block in enc/layer kernels (512 threads)
#define HP        32     // uints per bf16 h-row (64 cols * 2B = 128B)
#define NBLK      1024   // layer grid (must match stats_reduce: 8 x 128)
#define NGRP      (N_NODES / 4)
#define QSCALE    65536.0f
#define QINV      (1.0f / 65536.0f)

// 16B-group XOR swizzle within a row (R8's proven form)
__device__ __forceinline__ int swz(int c, int g) { return g ^ (c & 15); }

// fp32 -> bf16 (RNE), returned in low 16 bits
__device__ __forceinline__ unsigned bf16rne(float x)
{
    unsigned u = __float_as_uint(x);
    return (u + 0x7fffu + ((u >> 16) & 1u)) >> 16;
}
// unpack bf16 pair: .x = low half (even col), .y = high half (odd col)
__device__ __forceinline__ float2 bf2(unsigned u)
{
    float2 r;
    r.x = __uint_as_float(u << 16);
    r.y = __uint_as_float(u & 0xffff0000u);
    return r;
}

// BN affine consts from float stats (all-float: no doubles in layer kernel)
__device__ __forceinline__ void bn_constf(const float* __restrict__ stats,
                                          const float* __restrict__ gamma,
                                          const float* __restrict__ beta,
                                          int c, float& A, float& B)
{
    const float invN = 1.0f / (float)N_NODES;
    float mean = stats[c] * invN;
    float var  = stats[HIDDEN + c] * invN - mean * mean;
    float inv  = rsqrtf(fmaxf(var, 0.f) + BN_EPS);
    A = inv * gamma[c];
    B = beta[c] - mean * A;
}

// ---------------- encoder: h = x @ enc_w + enc_b -> bf16 h -----------------
__global__ __launch_bounds__(512, 6) void enc_kernel(
    const float* __restrict__ x, const float* __restrict__ w,
    const float* __restrict__ b, unsigned* __restrict__ h,
    int* __restrict__ deg)
{
    __shared__ __align__(16) float wT[HIDDEN * N_FEAT];        // 32 KB swizzled
    __shared__ __align__(16) float xb[LWAVES][4][N_FEAT];      // 16 KB
    {   // fold: zero deg for the CSR histogram
        int g = blockIdx.x * 512 + threadIdx.x;
        if (g < N_NODES) deg[g] = 0;
    }
    for (int i = threadIdx.x; i < N_FEAT * HIDDEN; i += 512) {
        int k = i >> 6, c = i & 63;
        wT[c * 128 + swz(c, k >> 2) * 4 + (k & 3)] = w[i];
    }
    const int lane = threadIdx.x & 63;
    const int wv   = threadIdx.x >> 6;
    const int sz   = lane & 15;
    const int r2   = lane >> 5;          // 0..1
    const int cc   = (lane & 31) * 4;    // 0..124
    const float bias = b[lane];
    __syncthreads();
    const int nwaves = gridDim.x * LWAVES;
    for (int grp = blockIdx.x * LWAVES + wv; grp < NGRP; grp += nwaves) {
        const int nbase = grp * 4;
        float4 v0 = *(const float4*)&x[(size_t)(nbase + r2) * N_FEAT + cc];
        float4 v1 = *(const float4*)&x[(size_t)(nbase + 2 + r2) * N_FEAT + cc];
        *((float4*)&xb[wv][r2][cc])     = v0;
        *((float4*)&xb[wv][2 + r2][cc]) = v1;
        float o0 = bias, o1 = bias, o2 = bias, o3 = bias;
        #pragma unroll 8
        for (int kc = 0; kc < N_FEAT / 4; ++kc) {
            float4 w4 = *(const float4*)&wT[lane * 128 + ((kc ^ sz) << 2)];
            float4 z0 = *(const float4*)&xb[wv][0][4 * kc];
            float4 z1 = *(const float4*)&xb[wv][1][4 * kc];
            float4 z2 = *(const float4*)&xb[wv][2][4 * kc];
            float4 z3 = *(const float4*)&xb[wv][3][4 * kc];
            o0 = fmaf(w4.x, z0.x, fmaf(w4.y, z0.y, fmaf(w4.z, z0.z, fmaf(w4.w, z0.w, o0))));
            o1 = fmaf(w4.x, z1.x, fmaf(w4.y, z1.y, fmaf(w4.z, z1.z, fmaf(w4.w, z1.w, o1))));
            o2 = fmaf(w4.x, z2.x, fmaf(w4.y, z2.y, fmaf(w4.z, z2.z, fmaf(w4.w, z2.w, o2))));
            o3 = fmaf(w4.x, z3.x, fmaf(w4.y, z3.y, fmaf(w4.z, z3.z, fmaf(w4.w, z3.w, o3))));
        }
        float t0 = __shfl_xor(o0, 1), t1 = __shfl_xor(o1, 1);
        float t2 = __shfl_xor(o2, 1), t3 = __shfl_xor(o3, 1);
        if (!(lane & 1)) {
            int p = lane >> 1;
            h[(size_t)(nbase + 0) * HP + p] = bf16rne(o0) | (bf16rne(t0) << 16);
            h[(size_t)(nbase + 1) * HP + p] = bf16rne(o1) | (bf16rne(t1) << 16);
            h[(size_t)(nbase + 2) * HP + p] = bf16rne(o2) | (bf16rne(t2) << 16);
            h[(size_t)(nbase + 3) * HP + p] = bf16rne(o3) | (bf16rne(t3) << 16);
        }
    }
}

// ---------------- CSR build ------------------------------------------------
__global__ __launch_bounds__(256) void hist_kernel(const int* __restrict__ ei,
                                                   int* __restrict__ deg)
{
    int e = blockIdx.x * 256 + threadIdx.x;
    if (e < N_EDGES) atomicAdd(&deg[ei[N_EDGES + e]], 1);
}

__global__ __launch_bounds__(256) void scan1_kernel(const int* __restrict__ deg,
                                                    int* __restrict__ row_start,
                                                    int* __restrict__ bsum)
{
    __shared__ int s[256];
    const int tid = threadIdx.x;
    const int gid = blockIdx.x * 256 + tid;
    int v = (gid < N_NODES) ? deg[gid] : 0;
    s[tid] = v;
    __syncthreads();
    for (int off = 1; off < 256; off <<= 1) {
        int t = (tid >= off) ? s[tid - off] : 0;
        __syncthreads();
        if (tid >= off) s[tid] += t;
        __syncthreads();
    }
    if (gid < N_NODES) row_start[gid] = s[tid] - v;
    if (tid == 255) bsum[blockIdx.x] = s[255];
}

__global__ __launch_bounds__(256) void scan2_kernel(int* __restrict__ bsum,
                                                    int* __restrict__ row_start)
{
    __shared__ int s[256];
    const int tid = threadIdx.x;
    int v = (tid < SCAN_BLK) ? bsum[tid] : 0;
    s[tid] = v;
    __syncthreads();
    for (int off = 1; off < 256; off <<= 1) {
        int t = (tid >= off) ? s[tid - off] : 0;
        __syncthreads();
        if (tid >= off) s[tid] += t;
        __syncthreads();
    }
    if (tid < SCAN_BLK) bsum[tid] = s[tid] - v;
    if (tid == 255) row_start[N_NODES] = s[255];
}

__global__ __launch_bounds__(256) void scan3_kernel(int* __restrict__ row_start,
                                                    const int* __restrict__ bsum,
                                                    int* __restrict__ cursor)
{
    int gid = blockIdx.x * 256 + threadIdx.x;
    if (gid < N_NODES) {
        int v = row_start[gid] + bsum[blockIdx.x];
        row_start[gid] = v;
        cursor[gid] = v;
    }
}

__global__ __launch_bounds__(256) void fill_kernel(const int* __restrict__ ei,
                                                   int* __restrict__ cursor,
                                                   int* __restrict__ csr_src)
{
    int e = blockIdx.x * 256 + threadIdx.x;
    if (e >= N_EDGES) return;
    int d = ei[N_EDGES + e];
    int pos = atomicAdd(&cursor[d], 1);
    csr_src[pos] = ei[e];
}

// ---------------- fused GIN layer — R8's measured-best (all-float stats) ----
// Simple one-load-per-j-step gather, BN+ReLU folded into gathered reads,
// int32 fixed-point gather accumulate (permutation-invariant), per-block
// FLOAT partials (fixed slot + fixed order -> deterministic, no atomics).
template<bool HASBN>
__global__ __launch_bounds__(512, 8) void layer_kernel(
    const unsigned* __restrict__ hin, const int* __restrict__ csr_src,
    const int* __restrict__ row_start,
    const float* __restrict__ stats_prev,
    const float* __restrict__ gamma, const float* __restrict__ beta,
    const float* __restrict__ eps, int layer,
    const float* __restrict__ w1, const float* __restrict__ b1,
    const float* __restrict__ w2, const float* __restrict__ b2,
    unsigned* __restrict__ hout, float* __restrict__ partials)
{
    __shared__ __align__(16) float wT1[HIDDEN * HIDDEN];       // 16 KB swizzled
    __shared__ __align__(16) float wT2[HIDDEN * HIDDEN];       // 16 KB swizzled
    __shared__ __align__(16) float zb[LWAVES][4][HIDDEN];      // 8 KB wave-private
    for (int i = threadIdx.x; i < HIDDEN * HIDDEN; i += 512) {
        int k = i >> 6, c = i & 63;
        int dst = c * 64 + swz(c, k >> 2) * 4 + (k & 3);
        wT1[dst] = w1[i];
        wT2[dst] = w2[i];
    }
    const int lane = threadIdx.x & 63;
    const int wv   = threadIdx.x >> 6;
    const int o    = lane >> 3;          // 0..7: row within oct
    const int c8   = (lane & 7) * 4;     // uint offset in row (8 bf16 cols)
    const int cb   = c8 * 2;
    const int sz   = lane & 15;
    float Ag[8], Bg[8];
    #pragma unroll
    for (int t = 0; t < 8; ++t) { Ag[t] = 1.f; Bg[t] = 0.f; }
    if (HASBN) {
        #pragma unroll
        for (int t = 0; t < 8; ++t)
            bn_constf(stats_prev, gamma, beta, cb + t, Ag[t], Bg[t]);
    }
    const float sf  = 1.0f + eps[layer];
    const float b1c = b1[lane], b2c = b2[lane];
    __syncthreads();

    float s = 0.f, s2 = 0.f;
    const int nwaves = gridDim.x * LWAVES;
    for (int grp = blockIdx.x * LWAVES + wv; grp < NGRP; grp += nwaves) {
        const int nbase = grp * 4;
        #pragma unroll
        for (int n = 0; n < 4; ++n) {
            const int node = nbase + n;
            const int s0 = row_start[node];
            const int s1 = row_start[node + 1];
            int a[8];
            #pragma unroll
            for (int t = 0; t < 8; ++t) a[t] = 0;
            for (int jb = s0; jb < s1; jb += 64) {
                int m = s1 - jb; if (m > 64) m = 64;
                int idx = csr_src[jb + (lane < m ? lane : m - 1)];
                int mm = m & ~7;
                for (int j = 0; j < mm; j += 8) {
                    int i = __shfl(idx, j + o);
                    uint4 u = *(const uint4*)&hin[(size_t)i * HP + c8];
                    float2 f0 = bf2(u.x), f1 = bf2(u.y), f2 = bf2(u.z), f3 = bf2(u.w);
                    float v[8] = {f0.x, f0.y, f1.x, f1.y, f2.x, f2.y, f3.x, f3.y};
                    #pragma unroll
                    for (int t = 0; t < 8; ++t) {
                        float f = v[t];
                        if (HASBN) f = fmaxf(fmaf(f, Ag[t], Bg[t]), 0.f);
                        a[t] += (int)(f * QSCALE);
                    }
                }
                int r8 = m & 7;
                if (r8) {
                    int sl = mm + o;
                    int i = __shfl(idx, sl < m ? sl : m - 1);
                    if (o < r8) {
                        uint4 u = *(const uint4*)&hin[(size_t)i * HP + c8];
                        float2 f0 = bf2(u.x), f1 = bf2(u.y), f2 = bf2(u.z), f3 = bf2(u.w);
                        float v[8] = {f0.x, f0.y, f1.x, f1.y, f2.x, f2.y, f3.x, f3.y};
                        #pragma unroll
                        for (int t = 0; t < 8; ++t) {
                            float f = v[t];
                            if (HASBN) f = fmaxf(fmaf(f, Ag[t], Bg[t]), 0.f);
                            a[t] += (int)(f * QSCALE);
                        }
                    }
                }
            }
            // oct reduction (int: exact, order-free)
            #pragma unroll
            for (int t = 0; t < 8; ++t) {
                a[t] += __shfl_xor(a[t], 8);
                a[t] += __shfl_xor(a[t], 16);
                a[t] += __shfl_xor(a[t], 32);
            }
            // self term + write z row (lanes 0..7 hold the full row)
            if (o == 0) {
                uint4 su = *(const uint4*)&hin[(size_t)node * HP + c8];
                float2 g0 = bf2(su.x), g1 = bf2(su.y), g2 = bf2(su.z), g3 = bf2(su.w);
                float svv[8] = {g0.x, g0.y, g1.x, g1.y, g2.x, g2.y, g3.x, g3.y};
                float zo[8];
                #pragma unroll
                for (int t = 0; t < 8; ++t) {
                    float f = svv[t];
                    if (HASBN) f = fmaxf(fmaf(f, Ag[t], Bg[t]), 0.f);
                    zo[t] = fmaf(sf, f, (float)a[t] * QINV);
                }
                float4 q0 = {zo[0], zo[1], zo[2], zo[3]};
                float4 q1 = {zo[4], zo[5], zo[6], zo[7]};
                *((float4*)&zb[wv][n][cb])     = q0;
                *((float4*)&zb[wv][n][cb + 4]) = q1;
            }
        }
        // ---- MLP1: o = relu(z @ w1 + b1) ----
        float o0 = b1c, o1 = b1c, o2 = b1c, o3 = b1c;
        #pragma unroll 4
        for (int kc = 0; kc < HIDDEN / 4; ++kc) {
            float4 w4 = *(const float4*)&wT1[lane * 64 + ((kc ^ sz) << 2)];
            float4 z0 = *(const float4*)&zb[wv][0][4 * kc];
            float4 z1 = *(const float4*)&zb[wv][1][4 * kc];
            float4 z2 = *(const float4*)&zb[wv][2][4 * kc];
            float4 z3 = *(const float4*)&zb[wv][3][4 * kc];
            o0 = fmaf(w4.x, z0.x, fmaf(w4.y, z0.y, fmaf(w4.z, z0.z, fmaf(w4.w, z0.w, o0))));
            o1 = fmaf(w4.x, z1.x, fmaf(w4.y, z1.y, fmaf(w4.z, z1.z, fmaf(w4.w, z1.w, o1))));
            o2 = fmaf(w4.x, z2.x, fmaf(w4.y, z2.y, fmaf(w4.z, z2.z, fmaf(w4.w, z2.w, o2))));
            o3 = fmaf(w4.x, z3.x, fmaf(w4.y, z3.y, fmaf(w4.z, z3.z, fmaf(w4.w, z3.w, o3))));
        }
        zb[wv][0][lane] = fmaxf(o0, 0.f);
        zb[wv][1][lane] = fmaxf(o1, 0.f);
        zb[wv][2][lane] = fmaxf(o2, 0.f);
        zb[wv][3][lane] = fmaxf(o3, 0.f);
        // ---- MLP2: p = y @ w2 + b2 ----
        float p0 = b2c, p1 = b2c, p2 = b2c, p3 = b2c;
        #pragma unroll 4
        for (int kc = 0; kc < HIDDEN / 4; ++kc) {
            float4 w4 = *(const float4*)&wT2[lane * 64 + ((kc ^ sz) << 2)];
            float4 z0 = *(const float4*)&zb[wv][0][4 * kc];
            float4 z1 = *(const float4*)&zb[wv][1][4 * kc];
            float4 z2 = *(const float4*)&zb[wv][2][4 * kc];
            float4 z3 = *(const float4*)&zb[wv][3][4 * kc];
            p0 = fmaf(w4.x, z0.x, fmaf(w4.y, z0.y, fmaf(w4.z, z0.z, fmaf(w4.w, z0.w, p0))));
            p1 = fmaf(w4.x, z1.x, fmaf(w4.y, z1.y, fmaf(w4.z, z1.z, fmaf(w4.w, z1.w, p1))));
            p2 = fmaf(w4.x, z2.x, fmaf(w4.y, z2.y, fmaf(w4.z, z2.z, fmaf(w4.w, z2.w, p2))));
            p3 = fmaf(w4.x, z3.x, fmaf(w4.y, z3.y, fmaf(w4.z, z3.z, fmaf(w4.w, z3.w, p3))));
        }
        float t0 = __shfl_xor(p0, 1), t1 = __shfl_xor(p1, 1);
        float t2 = __shfl_xor(p2, 1), t3 = __shfl_xor(p3, 1);
        if (!(lane & 1)) {
            int p = lane >> 1;
            hout[(size_t)(nbase + 0) * HP + p] = bf16rne(p0) | (bf16rne(t0) << 16);
            hout[(size_t)(nbase + 1) * HP + p] = bf16rne(p1) | (bf16rne(t1) << 16);
            hout[(size_t)(nbase + 2) * HP + p] = bf16rne(p2) | (bf16rne(t2) << 16);
            hout[(size_t)(nbase + 3) * HP + p] = bf16rne(p3) | (bf16rne(t3) << 16);
        }
        s  += ((p0 + p1) + (p2 + p3));
        s2 += ((p0 * p0 + p1 * p1) + (p2 * p2 + p3 * p3));
    }
    // ---- block-level float reduction -> per-block partial (fixed order) ----
    __syncthreads();
    float* red = &zb[0][0][0];
    red[threadIdx.x] = s;
    red[512 + threadIdx.x] = s2;
    __syncthreads();
    if (wv == 0) {
        float ts = 0.f, ts2 = 0.f;
        #pragma unroll
        for (int wq = 0; wq < LWAVES; ++wq) {
            ts  += red[wq * 64 + lane];
            ts2 += red[512 + wq * 64 + lane];
        }
        partials[(size_t)blockIdx.x * 128 + lane]      = ts;
        partials[(size_t)blockIdx.x * 128 + 64 + lane] = ts2;
    }
}

// ---------------- deterministic stats reduction: 1024 partials -> stats ----
__global__ __launch_bounds__(1024) void stats_reduce_kernel(
    const float* __restrict__ partials, float* __restrict__ stats)
{
    __shared__ float red[8][128];
    const int c = threadIdx.x & 127;
    const int k = threadIdx.x >> 7;     // 0..7: chunk of 128 blocks
    float s = 0.f;
    #pragma unroll 4
    for (int b = k * 128; b < (k + 1) * 128; ++b)   // fixed order
        s += partials[(size_t)b * 128 + c];
    red[k][c] = s;
    __syncthreads();
    if (k == 0) {
        float t = 0.f;
        #pragma unroll
        for (int kk = 0; kk < 8; ++kk) t += red[kk][c];  // fixed order
        stats[c] = t;
    }
}

__device__ __forceinline__ int lbound(const int* __restrict__ a, int n, int v)
{
    int lo = 0, hi = n;
    while (lo < hi) { int m = (lo + hi) >> 1; if (a[m] < v) lo = m + 1; else hi = m; }
    return lo;
}

// ---------------- mean pool per graph + final linear (fused) ---------------
__global__ __launch_bounds__(256) void pool_out_kernel(
    const unsigned* __restrict__ hpre, const int* __restrict__ batch,
    const float* __restrict__ stats, const float* __restrict__ gamma,
    const float* __restrict__ beta, const float* __restrict__ lw,
    const float* __restrict__ lb, float* __restrict__ out)
{
    __shared__ int bounds[2];
    __shared__ float red[256];
    __shared__ float pv[64];
    const int g = blockIdx.x;
    if (threadIdx.x < 2)
        bounds[threadIdx.x] = lbound(batch, N_NODES, g + threadIdx.x);
    __syncthreads();
    const int start = bounds[0], end = bounds[1];
    const int col = threadIdx.x & 63;
    const int row = threadIdx.x >> 6;
    float A, B;
    bn_constf(stats, gamma, beta, col, A, B);
    float s = 0.f;
    for (int r = start + row; r < end; r += 4) {
        unsigned u = hpre[(size_t)r * HP + (col >> 1)];
        float v = (col & 1) ? __uint_as_float(u & 0xffff0000u)
                            : __uint_as_float(u << 16);
        s += fmaxf(fmaf(v, A, B), 0.f);
    }
    red[threadIdx.x] = s;
    __syncthreads();
    if (row == 0) {
        float t = red[col] + red[64 + col] + red[128 + col] + red[192 + col];
        pv[col] = t / fmaxf((float)(end - start), 1.0f);
    }
    __syncthreads();
    if (threadIdx.x < N_CLASSES) {
        float acc = lb[threadIdx.x];
        #pragma unroll 16
        for (int j = 0; j < HIDDEN; ++j)
            acc = fmaf(pv[j], lw[j * N_CLASSES + threadIdx.x], acc);
        out[g * N_CLASSES + threadIdx.x] = acc;
    }
}

extern "C" void kernel_launch(void* const* d_in, const int* in_sizes, int n_in,
                              void* d_out, int out_size, void* d_ws, size_t ws_size,
                              hipStream_t stream)
{
    const float* x       = (const float*)d_in[0];
    const int*   ei      = (const int*)d_in[1];   // [2, N_EDGES]: src then dst
    const int*   batch   = (const int*)d_in[2];
    const float* enc_w   = (const float*)d_in[3];
    const float* enc_b   = (const float*)d_in[4];
    const float* eps     = (const float*)d_in[5];
    const float* conv_w1 = (const float*)d_in[6];
    const float* conv_b1 = (const float*)d_in[7];
    const float* conv_w2 = (const float*)d_in[8];
    const float* conv_b2 = (const float*)d_in[9];
    const float* bn_g    = (const float*)d_in[10];
    const float* bn_b    = (const float*)d_in[11];
    const float* lin_w   = (const float*)d_in[12];
    const float* lin_b   = (const float*)d_in[13];
    float* out = (float*)d_out;

    char* ws = (char*)d_ws;
    const size_t HB = (size_t)N_NODES * HP * sizeof(unsigned);  // 6.4 MB bf16 rows
    size_t off = 0;
    unsigned* P    = (unsigned*)(ws + off); off += HB;       // ping
    unsigned* Q    = (unsigned*)(ws + off); off += HB;       // pong
    float* stats   = (float*)(ws + off); off += N_LAYERS * 2 * HIDDEN * sizeof(float);
    float* partials= (float*)(ws + off); off += (size_t)NBLK * 128 * sizeof(float); // 512 KB
    int* deg       = (int*)(ws + off); off += 50176 * sizeof(int);
    int* row_start = (int*)(ws + off); off += 50176 * sizeof(int);   // N_NODES+1 used
    int* cursor    = (int*)(ws + off); off += 50176 * sizeof(int);
    int* bsum      = (int*)(ws + off); off += 256 * sizeof(int);
    int* csr_src   = (int*)(ws + off); off += (size_t)N_EDGES * sizeof(int);

    // enc zeroes deg (stream-ordered before hist); partials fully overwritten
    // by every layer dispatch (all NBLK blocks write their slot) -> no memsets.
    enc_kernel<<<768, 512, 0, stream>>>(x, enc_w, enc_b, P, deg);

    hist_kernel<<<(N_EDGES + 255) / 256, 256, 0, stream>>>(ei, deg);
    scan1_kernel<<<SCAN_BLK, 256, 0, stream>>>(deg, row_start, bsum);
    scan2_kernel<<<1, 256, 0, stream>>>(bsum, row_start);
    scan3_kernel<<<SCAN_BLK, 256, 0, stream>>>(row_start, bsum, cursor);
    fill_kernel<<<(N_EDGES + 255) / 256, 256, 0, stream>>>(ei, cursor, csr_src);

    const unsigned* curin = P;
    unsigned* curout = Q;
    for (int l = 0; l < N_LAYERS; ++l) {
        const float* w1 = conv_w1 + (size_t)l * HIDDEN * HIDDEN;
        const float* b1 = conv_b1 + (size_t)l * HIDDEN;
        const float* w2 = conv_w2 + (size_t)l * HIDDEN * HIDDEN;
        const float* b2 = conv_b2 + (size_t)l * HIDDEN;
        if (l == 0)
            layer_kernel<false><<<NBLK, 512, 0, stream>>>(
                curin, csr_src, row_start, nullptr, nullptr, nullptr,
                eps, l, w1, b1, w2, b2, curout, partials);
        else
            layer_kernel<true><<<NBLK, 512, 0, stream>>>(
                curin, csr_src, row_start,
                stats + (size_t)(l - 1) * 2 * HIDDEN,
                bn_g + (size_t)(l - 1) * HIDDEN, bn_b + (size_t)(l - 1) * HIDDEN,
                eps, l, w1, b1, w2, b2, curout, partials);
        stats_reduce_kernel<<<1, 1024, 0, stream>>>(partials,
                                                    stats + (size_t)l * 2 * HIDDEN);
        const unsigned* t = curout; curout = (unsigned*)curin; curin = t;
    }
    // after 3 layers: final pre-BN activations are in Q (P->Q->P->Q)

    pool_out_kernel<<<N_GRAPHS, 256, 0, stream>>>(
        Q, batch, stats + (size_t)(N_LAYERS - 1) * 2 * HIDDEN,
        bn_g + (size_t)(N_LAYERS - 1) * HIDDEN, bn_b + (size_t)(N_LAYERS - 1) * HIDDEN,
        lin_w, lin_b, out);
}